// Round 12
// baseline (100.414 us; speedup 1.0000x reference)
//
#include <hip/hip_runtime.h>
#include <math.h>

#define KOLD 128
#define KNEW 100
#define GPB  8          // row-groups (16 rows) per block

// LDS (bytes): 0: tmp_i 101 i32; 512: tmp_t 101 f32;
// 1024: F table = 4 waves x 4 rows x 104 dwords (416 B rows, 16B-aligned)
#define FT_OFF  1024
#define ROW_B   416
#define WAVE_B  (4 * ROW_B)
#define LDS_BYTES (FT_OFF + 4 * WAVE_B)

// ---- DPP 32-lane inclusive scan (pure VALU; validated R11) ----
template <int CTRL, int ROWM>
__device__ __forceinline__ float dpp_add(float v) {
    int s = __builtin_amdgcn_update_dpp(0, __float_as_int(v), CTRL, ROWM, 0xf, true);
    return v + __int_as_float(s);
}
__device__ __forceinline__ float scan32(float v) {
    v = dpp_add<0x111, 0xf>(v);   // row_shr:1
    v = dpp_add<0x112, 0xf>(v);   // row_shr:2
    v = dpp_add<0x114, 0xf>(v);   // row_shr:4
    v = dpp_add<0x118, 0xf>(v);   // row_shr:8
    v = dpp_add<0x142, 0xa>(v);   // row_bcast:15 into rows 1,3
    return v;
}
__device__ __forceinline__ float grp_total(float scanned, int half) {
    int t0 = __builtin_amdgcn_readlane(__float_as_int(scanned), 31);
    int t1 = __builtin_amdgcn_readlane(__float_as_int(scanned), 63);
    return __int_as_float(half ? t1 : t0);
}

__launch_bounds__(256, 8)
__global__ void rebin_k(const float* __restrict__ logits,
                        const float* __restrict__ oe,
                        const float* __restrict__ ne,
                        float* __restrict__ out, int nrows)
{
    __shared__ __align__(16) char lds[LDS_BYTES];
    int*   tmp_i = (int*)(lds + 0);
    float* tmp_t = (float*)(lds + 512);

    const int tid  = threadIdx.x;
    const int lane = tid & 63;
    const int wid  = tid >> 6;
    const int c    = lane & 31;    // column-quad: owns old bins 4c..4c+3
    const int half = lane >> 5;

    // ---- edge tables (once per block; amortized over GPB groups)
    if (tid <= KNEW) {
        float e = ne[tid];
        int i = 0;
#pragma unroll
        for (int st = 64; st >= 1; st >>= 1) {
            int cand = i + st;
            if (cand <= KOLD - 1 && oe[cand] <= e) i = cand;
        }
        float a = oe[i], b = oe[i + 1];
        float tt = (e - a) / (b - a);
        tmp_i[tid] = i;
        tmp_t[tid] = fminf(fmaxf(tt, 0.f), 1.f);
    }
    __syncthreads();

    // ---- per-lane edge meta in REGISTERS (row-independent, once per block):
    // k0 = first edge k with ibin[k] >= 4c; up to 4 owned edges.
    int k0 = 0;
#pragma unroll
    for (int st = 64; st >= 1; st >>= 1) {
        int cand = k0 + st;
        if (cand <= KNEW + 1 && tmp_i[cand - 1] < 4 * c) k0 = cand;
    }
    unsigned kb[4];   // byte offset of F slot (102*4 = pad dump for invalid)
    float    te[4];   // fractional t
    int      se[4];   // bin select 0..3
#pragma unroll
    for (int e = 0; e < 4; ++e) {
        int k  = k0 + e;
        int kc = k <= KNEW ? k : KNEW;
        int ib = tmp_i[kc];
        bool ok = (k <= KNEW) && (ib < 4 * c + 4);
        kb[e] = ok ? (unsigned)(k * 4) : 102u * 4u;
        te[e] = ok ? tmp_t[kc] : 0.f;
        se[e] = ok ? (ib - 4 * c) : 0;
    }

    char* fW = lds + FT_OFF + wid * WAVE_B;
    const int nm1 = nrows - 1;
    const int ngroups = (nrows + 15) >> 4;
    const float tiny = 1.1754943508222875e-38f;

#pragma unroll 1
    for (int kg = 0; kg < GPB; ++kg) {
        const int grp = blockIdx.x * GPB + kg;
        if (grp >= ngroups) break;
        const int wrow0 = grp * 16 + wid * 4;

        // ---- ideal-coalesced loads: chunk A rows wr0..+1, chunk B rows +2..+3
        const size_t offA = (size_t)min(wrow0 + half, nm1) * KOLD + c * 4;
        const size_t offB = (size_t)min(wrow0 + 2 + half, nm1) * KOLD + c * 4;
        const float4 vA = *(const float4*)(logits + offA);
        const float4 vB = *(const float4*)(logits + offB);

        // ---- chunk A: exp (no max-stab; med3 clamp), scan, F writes
        {
            const float e0 = __expf(fminf(fmaxf(vA.x, -80.f), 80.f));
            const float e1 = __expf(fminf(fmaxf(vA.y, -80.f), 80.f));
            const float e2 = __expf(fminf(fmaxf(vA.z, -80.f), 80.f));
            const float e3 = __expf(fminf(fmaxf(vA.w, -80.f), 80.f));
            const float sl = (e0 + e1) + (e2 + e3);
            const float ic = scan32(sl);
            const float tot = grp_total(ic, half);
            float rc = __builtin_amdgcn_rcpf(tot);
            const float inv = rc * (2.0f - tot * rc);
            const float p0 = ic - sl;
            const float p1 = p0 + e0, p2 = p1 + e1, p3 = p2 + e2;
            char* frow = fW + half * ROW_B;
#pragma unroll
            for (int e = 0; e < 4; ++e) {
                const float f0 = fmaf(te[e], e0, p0);
                const float f1 = fmaf(te[e], e1, p1);
                const float f2 = fmaf(te[e], e2, p2);
                const float f3 = fmaf(te[e], e3, p3);
                const float g01 = (se[e] & 1) ? f1 : f0;
                const float g23 = (se[e] & 1) ? f3 : f2;
                const float F   = (se[e] & 2) ? g23 : g01;
                *(float*)(frow + kb[e]) = F * inv;
            }
        }
        // ---- chunk B
        {
            const float e0 = __expf(fminf(fmaxf(vB.x, -80.f), 80.f));
            const float e1 = __expf(fminf(fmaxf(vB.y, -80.f), 80.f));
            const float e2 = __expf(fminf(fmaxf(vB.z, -80.f), 80.f));
            const float e3 = __expf(fminf(fmaxf(vB.w, -80.f), 80.f));
            const float sl = (e0 + e1) + (e2 + e3);
            const float ic = scan32(sl);
            const float tot = grp_total(ic, half);
            float rc = __builtin_amdgcn_rcpf(tot);
            const float inv = rc * (2.0f - tot * rc);
            const float p0 = ic - sl;
            const float p1 = p0 + e0, p2 = p1 + e1, p3 = p2 + e2;
            char* frow = fW + (2 + half) * ROW_B;
#pragma unroll
            for (int e = 0; e < 4; ++e) {
                const float f0 = fmaf(te[e], e0, p0);
                const float f1 = fmaf(te[e], e1, p1);
                const float f2 = fmaf(te[e], e2, p2);
                const float f3 = fmaf(te[e], e3, p3);
                const float g01 = (se[e] & 1) ? f1 : f0;
                const float g23 = (se[e] & 1) ? f3 : f2;
                const float F   = (se[e] & 2) ? g23 : g01;
                *(float*)(frow + kb[e]) = F * inv;
            }
        }
        asm volatile("s_waitcnt lgkmcnt(0)" ::: "memory");  // wave-local F ready

        // ---- phase 2: 400 outputs = 100 tasks of 4 consecutive (never cross rows)
        float* gout = out + (size_t)wrow0 * KNEW;
#pragma unroll
        for (int it = 0; it < 2; ++it) {
            const int t  = it * 64 + lane;
            const int tc = t < 100 ? t : 99;
            const int r  = (tc * 41) >> 10;        // exact /25 for tc < 1024/41
            const int q  = tc - r * 25;
            const char* frow = fW + r * ROW_B + q * 16;
            const float4 F4 = *(const float4*)(frow);
            const float  F5 = *(const float*)(frow + 16);
            float4 o;
            o.x = __logf(fmaxf(F4.y - F4.x, 0.f) + tiny);
            o.y = __logf(fmaxf(F4.z - F4.y, 0.f) + tiny);
            o.z = __logf(fmaxf(F4.w - F4.z, 0.f) + tiny);
            o.w = __logf(fmaxf(F5  - F4.w, 0.f) + tiny);
            if (t < 100 && wrow0 + r < nrows)
                *(float4*)(gout + r * KNEW + q * 4) = o;
        }
        asm volatile("" ::: "memory");   // order reads before next iter's writes
    }
}

extern "C" void kernel_launch(void* const* d_in, const int* in_sizes, int n_in,
                              void* d_out, int out_size, void* d_ws, size_t ws_size,
                              hipStream_t stream) {
    const float* logits = (const float*)d_in[0];
    const float* oe     = (const float*)d_in[1];
    const float* ne     = (const float*)d_in[2];
    float* out          = (float*)d_out;
    const int nrows     = in_sizes[0] / KOLD;

    const int ngroups = (nrows + 15) / 16;
    const int blocks  = (ngroups + GPB - 1) / GPB;   // 128 rows per block
    rebin_k<<<blocks, 256, 0, stream>>>(logits, oe, ne, out, nrows);
}

// Round 14
// 83.185 us; speedup vs baseline: 1.2071x; 1.2071x over previous
//
#include <hip/hip_runtime.h>
#include <math.h>

#define KOLD 128
#define KNEW 100
#define GPB  8          // row-groups (16 rows) per block

typedef float f32x4 __attribute__((ext_vector_type(4)));   // native vec for nt-store

// LDS (bytes): 0: tmp_i 101 i32; 512: tmp_t 101 f32;
// 1024: F table = 4 waves x 4 rows x 104 dwords (416 B rows, 16B-aligned)
#define FT_OFF  1024
#define ROW_B   416
#define WAVE_B  (4 * ROW_B)
#define LDS_BYTES (FT_OFF + 4 * WAVE_B)

// ---- DPP 32-lane inclusive scan (pure VALU; validated R11/R12) ----
template <int CTRL, int ROWM>
__device__ __forceinline__ float dpp_add(float v) {
    int s = __builtin_amdgcn_update_dpp(0, __float_as_int(v), CTRL, ROWM, 0xf, true);
    return v + __int_as_float(s);
}
__device__ __forceinline__ float scan32(float v) {
    v = dpp_add<0x111, 0xf>(v);   // row_shr:1
    v = dpp_add<0x112, 0xf>(v);   // row_shr:2
    v = dpp_add<0x114, 0xf>(v);   // row_shr:4
    v = dpp_add<0x118, 0xf>(v);   // row_shr:8
    v = dpp_add<0x142, 0xa>(v);   // row_bcast:15 into rows 1,3
    return v;
}
__device__ __forceinline__ float grp_total(float scanned, int half) {
    int t0 = __builtin_amdgcn_readlane(__float_as_int(scanned), 31);
    int t1 = __builtin_amdgcn_readlane(__float_as_int(scanned), 63);
    return __int_as_float(half ? t1 : t0);
}

__launch_bounds__(256, 8)
__global__ void rebin_k(const float* __restrict__ logits,
                        const float* __restrict__ oe,
                        const float* __restrict__ ne,
                        float* __restrict__ out, int nrows)
{
    __shared__ __align__(16) char lds[LDS_BYTES];
    int*   tmp_i = (int*)(lds + 0);
    float* tmp_t = (float*)(lds + 512);

    const int tid  = threadIdx.x;
    const int lane = tid & 63;
    const int wid  = tid >> 6;
    const int c    = lane & 31;    // column-quad: owns old bins 4c..4c+3
    const int half = lane >> 5;

    // ---- edge tables (once per block; amortized over GPB groups)
    if (tid <= KNEW) {
        float e = ne[tid];
        int i = 0;
#pragma unroll
        for (int st = 64; st >= 1; st >>= 1) {
            int cand = i + st;
            if (cand <= KOLD - 1 && oe[cand] <= e) i = cand;
        }
        float a = oe[i], b = oe[i + 1];
        float tt = (e - a) / (b - a);
        tmp_i[tid] = i;
        tmp_t[tid] = fminf(fmaxf(tt, 0.f), 1.f);
    }
    __syncthreads();

    // ---- per-lane edge meta in REGISTERS (row-independent, once per block)
    int k0 = 0;
#pragma unroll
    for (int st = 64; st >= 1; st >>= 1) {
        int cand = k0 + st;
        if (cand <= KNEW + 1 && tmp_i[cand - 1] < 4 * c) k0 = cand;
    }
    unsigned kb[4];   // byte offset of F slot (102*4 = pad dump for invalid)
    float    te[4];   // fractional t
    int      se[4];   // bin select 0..3
#pragma unroll
    for (int e = 0; e < 4; ++e) {
        int k  = k0 + e;
        int kc = k <= KNEW ? k : KNEW;
        int ib = tmp_i[kc];
        bool ok = (k <= KNEW) && (ib < 4 * c + 4);
        kb[e] = ok ? (unsigned)(k * 4) : 102u * 4u;
        te[e] = ok ? tmp_t[kc] : 0.f;
        se[e] = ok ? (ib - 4 * c) : 0;
    }

    char* fW = lds + FT_OFF + wid * WAVE_B;
    const int nm1 = nrows - 1;
    const int ngroups = (nrows + 15) >> 4;
    const int gmax = ngroups - 1;
    const float tiny = 1.1754943508222875e-38f;
    const int grp0 = blockIdx.x * GPB;

    // ---- prologue: load group grp0 (clamped) into current regs
    float4 vA, vB;
    {
        const int g  = grp0 <= gmax ? grp0 : gmax;
        const int w0 = g * 16 + wid * 4;
        const size_t offA = (size_t)min(w0 + half, nm1) * KOLD + c * 4;
        const size_t offB = (size_t)min(w0 + 2 + half, nm1) * KOLD + c * 4;
        vA = *(const float4*)(logits + offA);
        vB = *(const float4*)(logits + offB);
    }

#pragma unroll 1
    for (int kg = 0; kg < GPB; ++kg) {
        const int grp = grp0 + kg;
        if (grp >= ngroups) break;
        const int wrow0 = grp * 16 + wid * 4;

        // ---- prefetch NEXT group's chunk (issued before any compute/clobber;
        //      in flight across this whole iteration — hides HBM/L3 latency)
        float4 nA, nB;
        {
            const int gn = (grp + 1) <= gmax ? (grp + 1) : gmax;
            const int wn = gn * 16 + wid * 4;
            const size_t offA = (size_t)min(wn + half, nm1) * KOLD + c * 4;
            const size_t offB = (size_t)min(wn + 2 + half, nm1) * KOLD + c * 4;
            nA = *(const float4*)(logits + offA);
            nB = *(const float4*)(logits + offB);
        }

        // ---- chunk A: exp (no max-stab; clamp guard), scan, F writes
        {
            const float e0 = __expf(fminf(fmaxf(vA.x, -80.f), 80.f));
            const float e1 = __expf(fminf(fmaxf(vA.y, -80.f), 80.f));
            const float e2 = __expf(fminf(fmaxf(vA.z, -80.f), 80.f));
            const float e3 = __expf(fminf(fmaxf(vA.w, -80.f), 80.f));
            const float sl = (e0 + e1) + (e2 + e3);
            const float ic = scan32(sl);
            const float tot = grp_total(ic, half);
            float rc = __builtin_amdgcn_rcpf(tot);
            const float inv = rc * (2.0f - tot * rc);
            const float p0 = ic - sl;
            const float p1 = p0 + e0, p2 = p1 + e1, p3 = p2 + e2;
            char* frow = fW + half * ROW_B;
#pragma unroll
            for (int e = 0; e < 4; ++e) {
                const float f0 = fmaf(te[e], e0, p0);
                const float f1 = fmaf(te[e], e1, p1);
                const float f2 = fmaf(te[e], e2, p2);
                const float f3 = fmaf(te[e], e3, p3);
                const float g01 = (se[e] & 1) ? f1 : f0;
                const float g23 = (se[e] & 1) ? f3 : f2;
                const float F   = (se[e] & 2) ? g23 : g01;
                *(float*)(frow + kb[e]) = F * inv;
            }
        }
        // ---- chunk B
        {
            const float e0 = __expf(fminf(fmaxf(vB.x, -80.f), 80.f));
            const float e1 = __expf(fminf(fmaxf(vB.y, -80.f), 80.f));
            const float e2 = __expf(fminf(fmaxf(vB.z, -80.f), 80.f));
            const float e3 = __expf(fminf(fmaxf(vB.w, -80.f), 80.f));
            const float sl = (e0 + e1) + (e2 + e3);
            const float ic = scan32(sl);
            const float tot = grp_total(ic, half);
            float rc = __builtin_amdgcn_rcpf(tot);
            const float inv = rc * (2.0f - tot * rc);
            const float p0 = ic - sl;
            const float p1 = p0 + e0, p2 = p1 + e1, p3 = p2 + e2;
            char* frow = fW + (2 + half) * ROW_B;
#pragma unroll
            for (int e = 0; e < 4; ++e) {
                const float f0 = fmaf(te[e], e0, p0);
                const float f1 = fmaf(te[e], e1, p1);
                const float f2 = fmaf(te[e], e2, p2);
                const float f3 = fmaf(te[e], e3, p3);
                const float g01 = (se[e] & 1) ? f1 : f0;
                const float g23 = (se[e] & 1) ? f3 : f2;
                const float F   = (se[e] & 2) ? g23 : g01;
                *(float*)(frow + kb[e]) = F * inv;
            }
        }
        asm volatile("s_waitcnt lgkmcnt(0)" ::: "memory");  // wave-local F ready

        // ---- phase 2: 400 outputs = 100 tasks of 4 consecutive cols
        float* gout = out + (size_t)wrow0 * KNEW;
#pragma unroll
        for (int it = 0; it < 2; ++it) {
            const int t  = it * 64 + lane;
            const int tc = t < 100 ? t : 99;
            const int r  = (tc * 41) >> 10;        // exact /25 for tc < 100
            const int q  = tc - r * 25;
            const char* frow = fW + r * ROW_B + q * 16;
            const float4 F4 = *(const float4*)(frow);
            const float  F5 = *(const float*)(frow + 16);
            f32x4 o;
            o.x = __logf(fmaxf(F4.y - F4.x, 0.f) + tiny);
            o.y = __logf(fmaxf(F4.z - F4.y, 0.f) + tiny);
            o.z = __logf(fmaxf(F4.w - F4.z, 0.f) + tiny);
            o.w = __logf(fmaxf(F5  - F4.w, 0.f) + tiny);
            if (t < 100 && wrow0 + r < nrows) {
                // non-temporal: output never re-read; keep L3 for the input
                __builtin_nontemporal_store(o, (f32x4*)(gout + r * KNEW + q * 4));
            }
        }
        asm volatile("" ::: "memory");   // order reads before next iter's F writes

        vA = nA; vB = nB;
    }
}

extern "C" void kernel_launch(void* const* d_in, const int* in_sizes, int n_in,
                              void* d_out, int out_size, void* d_ws, size_t ws_size,
                              hipStream_t stream) {
    const float* logits = (const float*)d_in[0];
    const float* oe     = (const float*)d_in[1];
    const float* ne     = (const float*)d_in[2];
    float* out          = (float*)d_out;
    const int nrows     = in_sizes[0] / KOLD;

    const int ngroups = (nrows + 15) / 16;
    const int blocks  = (ngroups + GPB - 1) / GPB;   // 128 rows per block
    rebin_k<<<blocks, 256, 0, stream>>>(logits, oe, ne, out, nrows);
}